// Round 1
// baseline (547.786 us; speedup 1.0000x reference)
//
#include <hip/hip_runtime.h>
#include <hip/hip_bf16.h>

// Problem constants (from setup_inputs): B=16, Tm=256, U=64, V=512
#define BB   16
#define TM   256
#define UU   64
#define U1   65
#define VV   512
#define NEGF (-1e30f)

__device__ __forceinline__ float lae(float x, float y) {
    float m = fmaxf(x, y);
    return m + __logf(__expf(x - m) + __expf(y - m));
}
__device__ __forceinline__ float lae3(float x, float y, float z) {
    float m = fmaxf(fmaxf(x, y), z);
    return m + __logf(__expf(x - m) + __expf(y - m) + __expf(z - m));
}

// ---------------- Kernel 1: log-softmax gather ----------------
// One wave per (b,t,u) row of V=512 logits. Writes blank_lp (b,t,u) and
// label_lp (b,t,u<U) into workspace.
__global__ __launch_bounds__(256) void k_lse(const float* __restrict__ acts,
                                             const int* __restrict__ labels,
                                             float* __restrict__ blank_lp,
                                             float* __restrict__ label_lp) {
    int wid = (blockIdx.x << 2) + (threadIdx.x >> 6);
    if (wid >= BB * TM * U1) return;
    int lane = threadIdx.x & 63;
    const float* base = acts + (size_t)wid * VV;
    float4 va = *reinterpret_cast<const float4*>(base + lane * 4);
    float4 vb = *reinterpret_cast<const float4*>(base + 256 + lane * 4);
    float m = fmaxf(fmaxf(fmaxf(va.x, va.y), fmaxf(va.z, va.w)),
                    fmaxf(fmaxf(vb.x, vb.y), fmaxf(vb.z, vb.w)));
#pragma unroll
    for (int o = 32; o; o >>= 1) m = fmaxf(m, __shfl_xor(m, o));
    float s = __expf(va.x - m) + __expf(va.y - m) + __expf(va.z - m) + __expf(va.w - m)
            + __expf(vb.x - m) + __expf(vb.y - m) + __expf(vb.z - m) + __expf(vb.w - m);
#pragma unroll
    for (int o = 32; o; o >>= 1) s += __shfl_xor(s, o);
    float lse = m + __logf(s);
    if (lane == 0) {
        blank_lp[wid] = va.x - lse;               // index 0 = BLANK
        int u = wid % U1;
        if (u < UU) {
            int bt = wid / U1;                    // = b*TM + t
            int b  = bt / TM;
            int li = labels[b * UU + u];          // in [1, V)
            label_lp[bt * UU + u] = base[li] - lse;  // L1-hot scalar re-read
        }
    }
}

// ---------------- Kernel 2: forward/backward DP + delay ----------------
// One block (one wave) per example. Anti-diagonal wavefront:
//   alpha[t,u] = LSE(alpha[t-1,u]+blank[t-1,u], alpha[t,u-1]+label[t,u-1])
//   beta[t,u]  = LSE(blank[t,u]+beta[t+1,u], label[t,u]+beta[t,u+1], exit[t,u])
// lane = u (0..63); the u=64 column lives in a wave-uniform register.
// alpha (u<64 only) cached in exactly 64 KB of LDS for the gamma pass.
__global__ __launch_bounds__(64) void k_dp(const float* __restrict__ blank_lp,
                                           const float* __restrict__ label_lp,
                                           const int* __restrict__ act_lens,
                                           const int* __restrict__ label_lens,
                                           float* __restrict__ partials) {
    __shared__ float s_alpha[TM * UU];            // 65536 B
    const int b    = blockIdx.x;
    const int lane = threadIdx.x;
    const float* bl  = blank_lp + (size_t)b * TM * U1;
    const float* lab = label_lp + (size_t)b * TM * UU;
    const int T = act_lens[b];
    const int L = label_lens[b];
    const int t_last = T - 1;

    // ---- alpha sweep ----
    float a   = (lane == 0) ? 0.0f : NEGF;        // diag d=0: alpha[0,0]=0
    float a64 = NEGF;                             // wave-uniform u=64 column
    float capture = NEGF, cap64 = NEGF;
    if (lane == 0) s_alpha[0] = 0.0f;
    for (int d = 1; d < TM + U1 - 1; ++d) {       // d = 1..319
        const int t = d - lane;
        const float left = __shfl_up(a, 1);       // alpha[t, lane-1]
        const float a63  = __shfl(a, 63);         // alpha[t64, 63] (prev diag)
        float anew = NEGF;
        if (t >= 0 && t < TM) {
            float up = (t >= 1)    ? a    + bl[(t - 1) * U1 + lane] : NEGF;
            float lt = (lane >= 1) ? left + lab[t * UU + (lane - 1)] : NEGF;
            anew = lae(up, lt);
        }
        const int t64 = d - 64;
        float a64new = a64;
        if (t64 >= 0 && t64 < TM) {
            float up64 = (t64 >= 1) ? a64 + bl[(t64 - 1) * U1 + 64] : NEGF;
            float lt64 = a63 + lab[t64 * UU + 63];
            a64new = lae(up64, lt64);             // uniform across lanes
        }
        a = anew; a64 = a64new;
        if (t >= 0 && t < TM) s_alpha[t * UU + lane] = a;
        if (t == t_last && lane == L) capture = a;
        if (t64 == t_last && L == 64) cap64 = a64;
    }
    const float aEnd = (L < UU) ? __shfl(capture, L) : cap64;
    const float logZ = aEnd + bl[t_last * U1 + L];

    // ---- beta sweep + fused gamma/delay ----
    float bt = NEGF, b64 = NEGF, dsum = 0.0f;
    const float inv_len = 1.0f / (float)T;
    for (int d = TM + U1 - 2; d >= 0; --d) {      // d = 319..0
        const int t = d - lane;
        float right = __shfl_down(bt, 1);         // beta[t, lane+1]
        if (lane == 63) right = b64;              // neighbor is u=64 column
        float bnew = NEGF;
        if (t >= 0 && t < TM) {
            const float blk = bl[t * U1 + lane];
            const float lp  = lab[t * UU + lane];
            const float ex  = (t == t_last && lane == L) ? blk : NEGF;
            bnew = lae3(blk + bt, lp + right, ex);
            // gamma(t, u=lane) = exp(alpha + label + beta[t,u+1] - logZ)
            dsum += __expf(s_alpha[t * UU + lane] + lp + right - logZ)
                    * ((float)t * inv_len);
        }
        const int t64 = d - 64;
        float b64new = b64;
        if (t64 >= 0 && t64 < TM) {
            const float blk64 = bl[t64 * U1 + 64];
            const float ex64  = (t64 == t_last && L == 64) ? blk64 : NEGF;
            b64new = lae(blk64 + b64, ex64);      // no label term at u=U
        }
        bt = bnew; b64 = b64new;
    }
#pragma unroll
    for (int o = 32; o; o >>= 1) dsum += __shfl_xor(dsum, o);
    if (lane == 0) {
        partials[2 * b + 0] = -logZ;              // loss_rnnt_b
        partials[2 * b + 1] = dsum;               // loss_delay_b
    }
}

// ---------------- Kernel 3: final reduction ----------------
__global__ void k_reduce(const float* __restrict__ partials, float* __restrict__ out) {
    if (threadIdx.x == 0 && blockIdx.x == 0) {
        float rn = 0.0f, dl = 0.0f;
        for (int b = 0; b < BB; ++b) {
            rn += partials[2 * b + 0];
            dl += partials[2 * b + 1];
        }
        out[0] = rn + dl;   // loss_total  (DELAY_SCALE = 1)
        out[1] = rn;        // loss_rnnt
        out[2] = dl;        // loss_delay
    }
}

extern "C" void kernel_launch(void* const* d_in, const int* in_sizes, int n_in,
                              void* d_out, int out_size, void* d_ws, size_t ws_size,
                              hipStream_t stream) {
    const float* acts       = (const float*)d_in[0];
    const int*   labels     = (const int*)d_in[1];
    const int*   act_lens   = (const int*)d_in[2];
    const int*   label_lens = (const int*)d_in[3];

    float* ws       = (float*)d_ws;
    float* blank_lp = ws;                                  // B*TM*U1 = 266240 f
    float* label_lp = blank_lp + BB * TM * U1;             // B*TM*U  = 262144 f
    float* partials = label_lp + BB * TM * UU;             // 32 f

    const int rows = BB * TM * U1;
    k_lse<<<(rows + 3) / 4, 256, 0, stream>>>(acts, labels, blank_lp, label_lp);
    k_dp<<<BB, 64, 0, stream>>>(blank_lp, label_lp, act_lens, label_lens, partials);
    k_reduce<<<1, 64, 0, stream>>>(partials, (float*)d_out);
}

// Round 2
// 333.910 us; speedup vs baseline: 1.6405x; 1.6405x over previous
//
#include <hip/hip_runtime.h>
#include <hip/hip_bf16.h>

// Problem constants (from setup_inputs): B=16, Tm=256, U=64, V=512
#define BB   16
#define TM   256
#define UU   64
#define U1   65
#define VV   512
#define ND   320          // padded diagonal-row count (d = t+u in 0..318, +1 spare)
#define NEGF (-1e30f)

__device__ __forceinline__ float lae(float x, float y) {
    float m = fmaxf(x, y);
    return m + __logf(__expf(x - m) + __expf(y - m));
}
__device__ __forceinline__ float lae3(float x, float y, float z) {
    float m = fmaxf(fmaxf(x, y), z);
    return m + __logf(__expf(x - m) + __expf(y - m) + __expf(z - m));
}

// ---------------- Kernel 0: pad fill ----------------
// blD/labP pads must be NEGF every call (harness poisons ws once, never again).
__global__ void k_fill(float* __restrict__ p, int n4) {
    int i = blockIdx.x * blockDim.x + threadIdx.x;
    if (i < n4) reinterpret_cast<float4*>(p)[i] = make_float4(NEGF, NEGF, NEGF, NEGF);
}

// ---------------- Kernel 1: log-softmax gather (diag-major writes) ----------
// One wave per (b,t,u) row of V=512 logits.
//   blD [b][d][u]   = blank_lp(t=d-u, u)   for u<64          (row stride 64)
//   labP[b][d][1+u] = label_lp(t=d-u, u)   for u<64, col0=pad (row stride 65)
//   bl64[b][t]      = blank_lp(t, 64)
__global__ __launch_bounds__(256) void k_lse(const float* __restrict__ acts,
                                             const int* __restrict__ labels,
                                             float* __restrict__ blD,
                                             float* __restrict__ labP,
                                             float* __restrict__ bl64) {
    int wid = (blockIdx.x << 2) + (threadIdx.x >> 6);
    if (wid >= BB * TM * U1) return;
    int lane = threadIdx.x & 63;
    const float* base = acts + (size_t)wid * VV;
    float4 va = *reinterpret_cast<const float4*>(base + lane * 4);
    float4 vb = *reinterpret_cast<const float4*>(base + 256 + lane * 4);
    float m = fmaxf(fmaxf(fmaxf(va.x, va.y), fmaxf(va.z, va.w)),
                    fmaxf(fmaxf(vb.x, vb.y), fmaxf(vb.z, vb.w)));
#pragma unroll
    for (int o = 32; o; o >>= 1) m = fmaxf(m, __shfl_xor(m, o));
    float s = __expf(va.x - m) + __expf(va.y - m) + __expf(va.z - m) + __expf(va.w - m)
            + __expf(vb.x - m) + __expf(vb.y - m) + __expf(vb.z - m) + __expf(vb.w - m);
#pragma unroll
    for (int o = 32; o; o >>= 1) s += __shfl_xor(s, o);
    float lse = m + __logf(s);
    if (lane == 0) {
        int u  = wid % U1;
        int bt = wid / U1;
        int t  = bt % TM;
        int b  = bt / TM;
        float blank = va.x - lse;                 // index 0 = BLANK
        if (u < UU) {
            int r = t + u;
            blD[((size_t)b * ND + r) * UU + u] = blank;
            int li = labels[b * UU + u];          // in [1, V)
            labP[((size_t)b * ND + r) * U1 + (u + 1)] = base[li] - lse;
        } else {
            bl64[b * TM + t] = blank;
        }
    }
}

// ---------------- Kernel 2: forward/backward DP + delay ----------------
// One wave per example. Anti-diagonal wavefront; lane = u (0..63); u=64 column
// in a wave-uniform register. All per-step global reads are contiguous rows,
// 4-deep register-prefetched. Pads (NEGF) remove validity guards.
__global__ __launch_bounds__(64) void k_dp(const float* __restrict__ blD_,
                                           const float* __restrict__ labP_,
                                           const float* __restrict__ bl64_,
                                           const int* __restrict__ act_lens,
                                           const int* __restrict__ label_lens,
                                           float* __restrict__ partials) {
    __shared__ float s_alpha[TM * UU];            // 64 KB, alpha in diag access
    __shared__ float s_bl64p[TM + 2];             // [0]=pad NEGF, [1+t]=bl64[t]
    const int b    = blockIdx.x;
    const int lane = threadIdx.x;
    const float* blD  = blD_  + (size_t)b * ND * UU;
    const float* labP = labP_ + (size_t)b * ND * U1;

    if (lane == 0) { s_bl64p[0] = NEGF; s_bl64p[TM + 1] = NEGF; }
    for (int i = lane; i < TM; i += 64) s_bl64p[i + 1] = bl64_[b * TM + i];
    __syncthreads();

    const int T = act_lens[b];
    const int L = label_lens[b];
    const int t_last = T - 1;
    const float inv_len = 1.0f / (float)T;

    // ---- alpha sweep: steps ss = 1..320 (step 320 is a harmless pad step) ----
    float a   = (lane == 0) ? 0.0f : NEGF;
    float a64 = NEGF, capture = NEGF, cap64 = NEGF;
    if (lane == 0) s_alpha[0] = 0.0f;

    float pb[4], pl[4], p6[4];                    // 4-deep rotating prefetch
#pragma unroll
    for (int i = 0; i < 4; ++i) {
        pb[i] = blD[i * UU + lane];               // row ss-1 for ss=1..4
        pl[i] = labP[i * U1 + lane];
        p6[i] = labP[i * U1 + 64];
    }
    for (int s = 1; s <= 317; s += 4) {
#pragma unroll
        for (int k = 0; k < 4; ++k) {
            const int ss = s + k;
            const int t  = ss - lane;
            const float left = __shfl_up(a, 1);   // alpha[t, lane-1]
            const float a63v = __shfl(a, 63);     // alpha[t64, 63]
            const float anew = lae(a + pb[k], left + pl[k]);
            const int t64 = ss - 64;
            const int i64 = t64 < 0 ? 0 : t64;    // s_bl64p idx: bl64[t64-1]
            const float c64 = s_bl64p[i64];
            a64 = lae(a64 + c64, a63v + p6[k]);   // wave-uniform u=64 column
            a = anew;
            if ((unsigned)t < TM) s_alpha[t * UU + lane] = a;
            if (t == t_last && lane == L) capture = a;
            if (t64 == t_last) cap64 = a64;
            int r = ss + 3; r = r > (ND - 1) ? (ND - 1) : r;   // prefetch ss+4
            pb[k] = blD[r * UU + lane];
            pl[k] = labP[r * U1 + lane];
            p6[k] = labP[r * U1 + 64];
        }
    }
    const float aE = (L < UU) ? __shfl(capture, L) : cap64;
    const float blankLast = (L < UU) ? blD[(t_last + L) * UU + L]
                                     : s_bl64p[t_last + 1];
    const float logZ = aE + blankLast;

    // ---- beta sweep + fused gamma/delay: steps ss = 319..0 ----
    float bt = NEGF, b64 = NEGF, dsum = 0.0f;
    float qb[4], ql[4];
#pragma unroll
    for (int i = 0; i < 4; ++i) {
        qb[i] = blD[(319 - i) * UU + lane];
        ql[i] = labP[(319 - i) * U1 + lane + 1];
    }
    for (int s = 319; s >= 3; s -= 4) {
#pragma unroll
        for (int k = 0; k < 4; ++k) {
            const int ss = s - k;
            const int t  = ss - lane;
            float right = __shfl_down(bt, 1);     // beta[t, lane+1]
            right = (lane == 63) ? b64 : right;   // neighbor is u=64 column
            const float bB = qb[k];               // blank(t, lane) or pad
            const float lB = ql[k];               // label(t, lane) or pad
            const float ex = (t == t_last && lane == L) ? bB : NEGF;
            const float bnew = lae3(bB + bt, lB + right, ex);
            // gamma(t,u=lane) = exp(alpha + label + beta[t,u+1] - logZ)
            const float sA = s_alpha[(t & (TM - 1)) * UU + lane];
            dsum = __fmaf_rn(__expf(sA + lB + right - logZ),
                             (float)t * inv_len, dsum);
            const int t64 = ss - 64;
            int i64 = t64 + 1; i64 = i64 < 0 ? 0 : i64;  // bl64[t64]
            const float c64 = s_bl64p[i64];
            const float ex64 = (t64 == t_last && L == UU) ? c64 : NEGF;
            b64 = lae(b64 + c64, ex64);           // no label term at u=U
            bt = bnew;
            int r = ss - 4; r = r < 0 ? 0 : r;    // prefetch ss-4
            qb[k] = blD[r * UU + lane];
            ql[k] = labP[r * U1 + lane + 1];
        }
    }
#pragma unroll
    for (int o = 32; o; o >>= 1) dsum += __shfl_xor(dsum, o);
    if (lane == 0) {
        partials[2 * b + 0] = -logZ;              // loss_rnnt_b
        partials[2 * b + 1] = dsum;               // loss_delay_b
    }
}

// ---------------- Kernel 3: final reduction ----------------
__global__ void k_reduce(const float* __restrict__ partials, float* __restrict__ out) {
    if (threadIdx.x == 0 && blockIdx.x == 0) {
        float rn = 0.0f, dl = 0.0f;
        for (int b = 0; b < BB; ++b) {
            rn += partials[2 * b + 0];
            dl += partials[2 * b + 1];
        }
        out[0] = rn + dl;   // loss_total  (DELAY_SCALE = 1)
        out[1] = rn;        // loss_rnnt
        out[2] = dl;        // loss_delay
    }
}

extern "C" void kernel_launch(void* const* d_in, const int* in_sizes, int n_in,
                              void* d_out, int out_size, void* d_ws, size_t ws_size,
                              hipStream_t stream) {
    const float* acts       = (const float*)d_in[0];
    const int*   labels     = (const int*)d_in[1];
    const int*   act_lens   = (const int*)d_in[2];
    const int*   label_lens = (const int*)d_in[3];

    float* ws       = (float*)d_ws;
    float* blD      = ws;                               // B*ND*UU = 327680 f
    float* labP     = blD + BB * ND * UU;               // B*ND*U1 = 332800 f
    float* bl64     = labP + (size_t)BB * ND * U1;      // B*TM    =   4096 f
    float* partials = bl64 + BB * TM;                   // 32 f
    // total ~2.66 MB of ws

    const int nfill4 = (BB * ND * UU + BB * ND * U1) / 4;   // blD+labP contiguous
    k_fill<<<(nfill4 + 255) / 256, 256, 0, stream>>>(ws, nfill4);

    const int rows = BB * TM * U1;
    k_lse<<<(rows + 3) / 4, 256, 0, stream>>>(acts, labels, blD, labP, bl64);
    k_dp<<<BB, 64, 0, stream>>>(blD, labP, bl64, act_lens, label_lens, partials);
    k_reduce<<<1, 64, 0, stream>>>(partials, (float*)d_out);
}

// Round 4
// 210.276 us; speedup vs baseline: 2.6051x; 1.5880x over previous
//
#include <hip/hip_runtime.h>
#include <hip/hip_bf16.h>

// Problem constants (from setup_inputs): B=16, Tm=256, U=64, V=512
#define BB   16
#define TM   256
#define UU   64
#define U1   65
#define VV   512
#define ND   320          // padded diagonal-row count (d = t+u in 0..318, +1 spare)
#define NEGF (-1e30f)
#define LOG2E 1.4426950408889634f
#define LN2   0.6931471805599453f

// log-add-exp in base-2 log space (inputs pre-scaled by log2e).
// exp2f/log2f lower to native v_exp_f32/v_log_f32 on gfx950.
__device__ __forceinline__ float lae2(float x, float y) {
    float m = fmaxf(x, y);
    return m + log2f(exp2f(x - m) + exp2f(y - m));
}

// ---------------- Kernel 0: pad fill ----------------
// blD/labP pads must be NEGF every call (harness poisons ws once, never again).
__global__ void k_fill(float* __restrict__ p, int n4) {
    int i = blockIdx.x * blockDim.x + threadIdx.x;
    if (i < n4) reinterpret_cast<float4*>(p)[i] = make_float4(NEGF, NEGF, NEGF, NEGF);
}

// ---------------- Kernel 1: log-softmax gather (diag-major, log2-scaled) ----
// One wave per (b,t,u) row of V=512 logits.
//   blD [b][d][u]   = log2e*blank_lp(t=d-u, u)  u<64          (row stride 64)
//   labP[b][d][1+u] = log2e*label_lp(t=d-u, u)  u<64, col0=pad (row stride 65)
//   bl64[b][t]      = log2e*blank_lp(t, 64)
__global__ __launch_bounds__(256) void k_lse(const float* __restrict__ acts,
                                             const int* __restrict__ labels,
                                             float* __restrict__ blD,
                                             float* __restrict__ labP,
                                             float* __restrict__ bl64) {
    int wid = (blockIdx.x << 2) + (threadIdx.x >> 6);
    if (wid >= BB * TM * U1) return;
    int lane = threadIdx.x & 63;
    const float* base = acts + (size_t)wid * VV;
    float4 va = *reinterpret_cast<const float4*>(base + lane * 4);
    float4 vb = *reinterpret_cast<const float4*>(base + 256 + lane * 4);
    float m = fmaxf(fmaxf(fmaxf(va.x, va.y), fmaxf(va.z, va.w)),
                    fmaxf(fmaxf(vb.x, vb.y), fmaxf(vb.z, vb.w)));
#pragma unroll
    for (int o = 32; o; o >>= 1) m = fmaxf(m, __shfl_xor(m, o));
    float s = __expf(va.x - m) + __expf(va.y - m) + __expf(va.z - m) + __expf(va.w - m)
            + __expf(vb.x - m) + __expf(vb.y - m) + __expf(vb.z - m) + __expf(vb.w - m);
#pragma unroll
    for (int o = 32; o; o >>= 1) s += __shfl_xor(s, o);
    float lse = m + __logf(s);
    if (lane == 0) {
        int u  = wid % U1;
        int bt = wid / U1;
        int t  = bt % TM;
        int b  = bt / TM;
        float blank = (va.x - lse) * LOG2E;       // index 0 = BLANK
        if (u < UU) {
            int r = t + u;
            blD[((size_t)b * ND + r) * UU + u] = blank;
            int li = labels[b * UU + u];          // in [1, V)
            labP[((size_t)b * ND + r) * U1 + (u + 1)] = (base[li] - lse) * LOG2E;
        } else {
            bl64[b * TM + t] = blank;
        }
    }
}

// ---------------- Kernel 2: concurrent fwd/bwd DP + fused delay ------------
// One block = 2 waves per example. Wave 0: alpha sweep (stores s_alpha).
// Wave 1: beta sweep (stores s_pr[t][u] = label+beta[t,u+1]). Then a joint
// 128-thread gamma pass over LDS. Lane = u; u=64 column in uniform registers.
// 8-deep register prefetch; NEGF pads remove validity guards.
__global__ __launch_bounds__(128) void k_dp(const float* __restrict__ blD_,
                                            const float* __restrict__ labP_,
                                            const float* __restrict__ bl64_,
                                            const int* __restrict__ act_lens,
                                            const int* __restrict__ label_lens,
                                            float* __restrict__ partials) {
    __shared__ float s_alpha[TM * UU];            // 64 KB
    __shared__ float s_pr[TM * UU];               // 64 KB
    __shared__ float s_bl64p[TM + 2];             // [0]=pad, [1+t]=bl64[t]
    __shared__ float s_logZ;
    __shared__ float s_red[2];
    const int b    = blockIdx.x;
    const int tid  = threadIdx.x;
    const int lane = tid & 63;
    const int wv   = tid >> 6;
    const float* blD  = blD_  + (size_t)b * ND * UU;
    const float* labP = labP_ + (size_t)b * ND * U1;

    if (tid == 0) { s_bl64p[0] = NEGF; s_bl64p[TM + 1] = NEGF; }
    for (int i = tid; i < TM; i += 128) s_bl64p[i + 1] = bl64_[b * TM + i];
    __syncthreads();

    const int T = act_lens[b];
    const int L = label_lens[b];
    const int t_last = T - 1;

    if (wv == 0) {
        // ---- alpha sweep: ss = 1..320 (319,320 are harmless pad steps) ----
        float a   = (lane == 0) ? 0.0f : NEGF;
        float a64 = NEGF, capture = NEGF, cap64 = NEGF;
        if (lane == 0) s_alpha[0] = 0.0f;
        float pb[8], pl[8], p6[8];
#pragma unroll
        for (int i = 0; i < 8; ++i) {
            pb[i] = blD[i * UU + lane];           // row ss-1 for ss=1..8
            pl[i] = labP[i * U1 + lane];
            p6[i] = labP[i * U1 + 64];
        }
        for (int s = 1; s <= 313; s += 8) {
#pragma unroll
            for (int k = 0; k < 8; ++k) {
                const int ss = s + k;
                const int t  = ss - lane;
                const float left = __shfl_up(a, 1);   // alpha[t, lane-1]
                const float a63v = __shfl(a, 63);     // alpha[t64, 63]
                const float anew = lae2(a + pb[k], left + pl[k]);
                const int t64 = ss - 64;
                const int i64 = t64 < 0 ? 0 : t64;    // s_bl64p[t64]=bl64[t64-1]
                a64 = lae2(a64 + s_bl64p[i64], a63v + p6[k]);
                a = anew;
                if ((unsigned)t < TM) s_alpha[t * UU + lane] = a;
                if (t == t_last && lane == L) capture = a;
                if (t64 == t_last) cap64 = a64;
                int r = ss + 7; r = r > (ND - 1) ? (ND - 1) : r;  // for ss+8
                pb[k] = blD[r * UU + lane];
                pl[k] = labP[r * U1 + lane];
                p6[k] = labP[r * U1 + 64];
            }
        }
        const float aE = (L < UU) ? __shfl(capture, L) : cap64;
        const float blankLast = (L < UU) ? blD[(t_last + L) * UU + L]
                                         : s_bl64p[t_last + 1];
        if (lane == 0) s_logZ = aE + blankLast;   // base-2 units
    } else {
        // ---- beta sweep: ss = 319..0 ----
        float bt = NEGF, b64 = NEGF;
        float qb[8], ql[8];
#pragma unroll
        for (int i = 0; i < 8; ++i) {
            qb[i] = blD[(319 - i) * UU + lane];
            ql[i] = labP[(319 - i) * U1 + lane + 1];
        }
        for (int s = 319; s >= 7; s -= 8) {
#pragma unroll
            for (int k = 0; k < 8; ++k) {
                const int ss = s - k;
                const int t  = ss - lane;
                float right = __shfl_down(bt, 1);     // beta[t, lane+1]
                right = (lane == 63) ? b64 : right;   // u=64 column neighbor
                const float bB = qb[k];               // blank(t,lane) or pad
                const float lB = ql[k];               // label(t,lane) or pad
                const float pr = lB + right;          // label + beta[t,u+1]
                float bnew = lae2(bB + bt, pr);
                if (t == t_last && lane == L) bnew = lae2(bnew, bB);  // exit
                if ((unsigned)t < TM) s_pr[t * UU + lane] = pr;
                const int t64 = ss - 64;
                int i64 = t64 + 1; i64 = i64 < 0 ? 0 : i64;  // bl64[t64]
                const float c64 = s_bl64p[i64];
                b64 = b64 + c64;                      // lae(x,-inf)=x
                if (t64 == t_last && L == UU) b64 = lae2(b64, c64);  // exit
                bt = bnew;
                int r = ss - 8; r = r < 0 ? 0 : r;
                qb[k] = blD[r * UU + lane];
                ql[k] = labP[r * U1 + lane + 1];
            }
        }
    }
    __syncthreads();

    // ---- gamma pass: dsum = sum exp2(alpha + pr - logZ) * t/T ----
    const float logZ = s_logZ;
    const float invT = 1.0f / (float)T;
    float dsum = 0.0f;
#pragma unroll 8
    for (int idx = tid; idx < TM * UU; idx += 128) {
        const int t = idx >> 6;
        dsum = __fmaf_rn(exp2f(s_alpha[idx] + s_pr[idx] - logZ),
                         (float)t * invT, dsum);
    }
#pragma unroll
    for (int o = 32; o; o >>= 1) dsum += __shfl_xor(dsum, o);
    if (lane == 0) s_red[wv] = dsum;
    __syncthreads();
    if (tid == 0) {
        partials[2 * b + 0] = -logZ * LN2;        // loss_rnnt_b (nat units)
        partials[2 * b + 1] = s_red[0] + s_red[1];
    }
}

// ---------------- Kernel 3: final reduction ----------------
__global__ void k_reduce(const float* __restrict__ partials, float* __restrict__ out) {
    if (threadIdx.x == 0 && blockIdx.x == 0) {
        float rn = 0.0f, dl = 0.0f;
        for (int b = 0; b < BB; ++b) {
            rn += partials[2 * b + 0];
            dl += partials[2 * b + 1];
        }
        out[0] = rn + dl;   // loss_total  (DELAY_SCALE = 1)
        out[1] = rn;        // loss_rnnt
        out[2] = dl;        // loss_delay
    }
}

extern "C" void kernel_launch(void* const* d_in, const int* in_sizes, int n_in,
                              void* d_out, int out_size, void* d_ws, size_t ws_size,
                              hipStream_t stream) {
    const float* acts       = (const float*)d_in[0];
    const int*   labels     = (const int*)d_in[1];
    const int*   act_lens   = (const int*)d_in[2];
    const int*   label_lens = (const int*)d_in[3];

    float* ws       = (float*)d_ws;
    float* blD      = ws;                               // B*ND*UU = 327680 f
    float* labP     = blD + BB * ND * UU;               // B*ND*U1 = 332800 f
    float* bl64     = labP + (size_t)BB * ND * U1;      // B*TM    =   4096 f
    float* partials = bl64 + BB * TM;                   // 32 f
    // total ~2.66 MB of ws

    const int nfill4 = (BB * ND * UU + BB * ND * U1) / 4;   // blD+labP contiguous
    k_fill<<<(nfill4 + 255) / 256, 256, 0, stream>>>(ws, nfill4);

    const int rows = BB * TM * U1;
    k_lse<<<(rows + 3) / 4, 256, 0, stream>>>(acts, labels, blD, labP, bl64);
    k_dp<<<BB, 128, 0, stream>>>(blD, labP, bl64, act_lens, label_lens, partials);
    k_reduce<<<1, 64, 0, stream>>>(partials, (float*)d_out);
}

// Round 5
// 185.549 us; speedup vs baseline: 2.9522x; 1.1333x over previous
//
#include <hip/hip_runtime.h>
#include <hip/hip_bf16.h>

// Problem constants (from setup_inputs): B=16, Tm=256, U=64, V=512
#define BB   16
#define TM   256
#define UU   64
#define U1   65
#define VV   512
#define ND   320          // padded diagonal-row count (d = t+u in 0..318, +1 spare)
#define WROW 128          // interleaved row width (floats)
#define NEGF (-1e30f)
#define LOG2E 1.4426950408889634f
#define LN2   0.6931471805599453f

// log-add-exp in base-2 log space (inputs pre-scaled by log2e).
__device__ __forceinline__ float lae2(float x, float y) {
    float m = fmaxf(x, y);
    return m + log2f(exp2f(x - m) + exp2f(y - m));
}

// ---------------- Kernel 0: pad fill ----------------
// Aarr/Barr/p6arr pads must be NEGF every call (ws poisoned once, never again).
__global__ void k_fill(float* __restrict__ p, int n4) {
    int i = blockIdx.x * blockDim.x + threadIdx.x;
    if (i < n4) reinterpret_cast<float4*>(p)[i] = make_float4(NEGF, NEGF, NEGF, NEGF);
}

// ---------------- Kernel 1: log-softmax gather (sweep-specialized layout) ---
// One wave per (b,t,u) row of V=512 logits. All values pre-scaled by log2e.
// Alpha-step operands:  Aarr[b][r][2l+0] = blank(r-l,   l)     (pb)
//                       Aarr[b][r][2l+1] = label(r-l+1, l-1)   (pl)
// Beta-step operands:   Barr[b][r][2l+0] = label(r-l, l)       (ql)
//                       Barr[b][r][2l+1] = blank(r-l, l)       (qb)
// u=64-column scalars:  p6arr[b][r] = label(r-63, 63),  bl64[b][t] = blank(t,64)
__global__ __launch_bounds__(256) void k_lse(const float* __restrict__ acts,
                                             const int* __restrict__ labels,
                                             float* __restrict__ Aarr,
                                             float* __restrict__ Barr,
                                             float* __restrict__ p6arr,
                                             float* __restrict__ bl64) {
    int wid = (blockIdx.x << 2) + (threadIdx.x >> 6);
    if (wid >= BB * TM * U1) return;
    int lane = threadIdx.x & 63;
    const float* base = acts + (size_t)wid * VV;
    float4 va = *reinterpret_cast<const float4*>(base + lane * 4);
    float4 vb = *reinterpret_cast<const float4*>(base + 256 + lane * 4);
    float m = fmaxf(fmaxf(fmaxf(va.x, va.y), fmaxf(va.z, va.w)),
                    fmaxf(fmaxf(vb.x, vb.y), fmaxf(vb.z, vb.w)));
#pragma unroll
    for (int o = 32; o; o >>= 1) m = fmaxf(m, __shfl_xor(m, o));
    float s = __expf(va.x - m) + __expf(va.y - m) + __expf(va.z - m) + __expf(va.w - m)
            + __expf(vb.x - m) + __expf(vb.y - m) + __expf(vb.z - m) + __expf(vb.w - m);
#pragma unroll
    for (int o = 32; o; o >>= 1) s += __shfl_xor(s, o);
    float lse = m + __logf(s);
    if (lane == 0) {
        int u  = wid % U1;
        int bt = wid / U1;
        int t  = bt % TM;
        int b  = bt / TM;
        float blank = (va.x - lse) * LOG2E;       // index 0 = BLANK
        if (u < UU) {
            int r = t + u;
            int li = labels[b * UU + u];          // in [1, V)
            float lab = (base[li] - lse) * LOG2E;
            size_t row = ((size_t)b * ND + r) * WROW;
            *reinterpret_cast<float2*>(Barr + row + 2 * u) = make_float2(lab, blank);
            Aarr[row + 2 * u] = blank;
            if (u < 63) Aarr[row + 2 * u + 3] = lab;   // slot l=u+1
            else        p6arr[b * ND + r]     = lab;   // u=63 label feeds a64
        } else {
            bl64[b * TM + t] = blank;
        }
    }
}

// ---------------- Kernel 2: concurrent fwd/bwd DP + fused delay ------------
// One block = 2 waves per example. Wave 0: alpha sweep (stores s_alpha).
// Wave 1: beta sweep (stores s_pr[t][u] = label+beta[t,u+1]). Then a joint
// 128-thread gamma pass over LDS. Lane = u; u=64 column in uniform registers.
// ONE float2 load per lane per step, 16-deep register prefetch.
__global__ __launch_bounds__(128) void k_dp(const float* __restrict__ Aarr_,
                                            const float* __restrict__ Barr_,
                                            const float* __restrict__ p6arr_,
                                            const float* __restrict__ bl64_,
                                            const int* __restrict__ act_lens,
                                            const int* __restrict__ label_lens,
                                            float* __restrict__ partials) {
    __shared__ float s_alpha[TM * UU];            // 64 KB
    __shared__ float s_pr[TM * UU];               // 64 KB
    __shared__ float s_bl64p[TM + 2];             // [0]=pad, [1+t]=bl64[t]
    __shared__ float s_p6[ND];                    // p6arr slice
    __shared__ float s_logZ;
    __shared__ float s_red[2];
    const int b    = blockIdx.x;
    const int tid  = threadIdx.x;
    const int lane = tid & 63;
    const int wv   = tid >> 6;
    const float* Aarr = Aarr_ + (size_t)b * ND * WROW;
    const float* Barr = Barr_ + (size_t)b * ND * WROW;

    if (tid == 0) { s_bl64p[0] = NEGF; s_bl64p[TM + 1] = NEGF; }
    for (int i = tid; i < TM; i += 128) s_bl64p[i + 1] = bl64_[b * TM + i];
    for (int i = tid; i < ND; i += 128) s_p6[i] = p6arr_[b * ND + i];
    __syncthreads();

    const int T = act_lens[b];
    const int L = label_lens[b];
    const int t_last = T - 1;

    if (wv == 0) {
        // ---- alpha sweep: ss = 1..320 (319,320 are harmless pad steps) ----
        float a   = (lane == 0) ? 0.0f : NEGF;
        float a64 = NEGF, capture = NEGF, cap64 = NEGF;
        if (lane == 0) s_alpha[0] = 0.0f;
        float2 P[16];
#pragma unroll
        for (int i = 0; i < 16; ++i)              // rows 0..15 for ss=1..16
            P[i] = *reinterpret_cast<const float2*>(Aarr + i * WROW + 2 * lane);
        for (int s = 1; s <= 305; s += 16) {
#pragma unroll
            for (int k = 0; k < 16; ++k) {
                const int ss = s + k;
                const int t  = ss - lane;
                const float left = __shfl_up(a, 1);   // alpha[t, lane-1]
                const float a63v = __shfl(a, 63);     // alpha[t64, 63]
                const float anew = lae2(a + P[k].x, left + P[k].y);
                const int t64 = ss - 64;
                const int i64 = t64 < 0 ? 0 : t64;    // s_bl64p[t64]=bl64[t64-1]
                a64 = lae2(a64 + s_bl64p[i64], a63v + s_p6[ss - 1]);
                a = anew;
                if ((unsigned)t < TM) s_alpha[t * UU + lane] = a;
                if (t == t_last && lane == L) capture = a;
                if (t64 == t_last) cap64 = a64;
                int r = ss + 15; r = r > (ND - 1) ? (ND - 1) : r;  // for ss+16
                P[k] = *reinterpret_cast<const float2*>(Aarr + r * WROW + 2 * lane);
            }
        }
        const float aE = (L < UU) ? __shfl(capture, L) : cap64;
        const float blankLast = (L < UU) ? Aarr[(t_last + L) * WROW + 2 * L]
                                         : s_bl64p[t_last + 1];
        if (lane == 0) s_logZ = aE + blankLast;   // base-2 units
    } else {
        // ---- beta sweep: ss = 319..0 ----
        float bt = NEGF, b64 = NEGF;
        float2 Q[16];
#pragma unroll
        for (int i = 0; i < 16; ++i)              // rows 319..304
            Q[i] = *reinterpret_cast<const float2*>(Barr + (319 - i) * WROW + 2 * lane);
        for (int s = 319; s >= 15; s -= 16) {
#pragma unroll
            for (int k = 0; k < 16; ++k) {
                const int ss = s - k;
                const int t  = ss - lane;
                float right = __shfl_down(bt, 1);     // beta[t, lane+1]
                right = (lane == 63) ? b64 : right;   // u=64 column neighbor
                const float lB = Q[k].x;              // label(t,lane) or pad
                const float bB = Q[k].y;              // blank(t,lane) or pad
                const float pr = lB + right;          // label + beta[t,u+1]
                float bnew = lae2(bB + bt, pr);
                if (t == t_last && lane == L) bnew = lae2(bnew, bB);  // exit
                if ((unsigned)t < TM) s_pr[t * UU + lane] = pr;
                const int t64 = ss - 64;
                int i64 = t64 + 1; i64 = i64 < 0 ? 0 : i64;  // bl64[t64]
                const float c64 = s_bl64p[i64];
                b64 = b64 + c64;                      // lae(x,-inf)=x
                if (t64 == t_last && L == UU) b64 = lae2(b64, c64);  // exit
                bt = bnew;
                int r = ss - 16; r = r < 0 ? 0 : r;
                Q[k] = *reinterpret_cast<const float2*>(Barr + r * WROW + 2 * lane);
            }
        }
    }
    __syncthreads();

    // ---- gamma pass: dsum = sum exp2(alpha + pr - logZ) * t/T ----
    const float logZ = s_logZ;
    const float invT = 1.0f / (float)T;
    float dsum = 0.0f;
#pragma unroll 8
    for (int idx = tid; idx < TM * UU; idx += 128) {
        const int t = idx >> 6;
        dsum = __fmaf_rn(exp2f(s_alpha[idx] + s_pr[idx] - logZ),
                         (float)t * invT, dsum);
    }
#pragma unroll
    for (int o = 32; o; o >>= 1) dsum += __shfl_xor(dsum, o);
    if (lane == 0) s_red[wv] = dsum;
    __syncthreads();
    if (tid == 0) {
        partials[2 * b + 0] = -logZ * LN2;        // loss_rnnt_b (nat units)
        partials[2 * b + 1] = s_red[0] + s_red[1];
    }
}

// ---------------- Kernel 3: final reduction ----------------
__global__ void k_reduce(const float* __restrict__ partials, float* __restrict__ out) {
    if (threadIdx.x == 0 && blockIdx.x == 0) {
        float rn = 0.0f, dl = 0.0f;
        for (int b = 0; b < BB; ++b) {
            rn += partials[2 * b + 0];
            dl += partials[2 * b + 1];
        }
        out[0] = rn + dl;   // loss_total  (DELAY_SCALE = 1)
        out[1] = rn;        // loss_rnnt
        out[2] = dl;        // loss_delay
    }
}

extern "C" void kernel_launch(void* const* d_in, const int* in_sizes, int n_in,
                              void* d_out, int out_size, void* d_ws, size_t ws_size,
                              hipStream_t stream) {
    const float* acts       = (const float*)d_in[0];
    const int*   labels     = (const int*)d_in[1];
    const int*   act_lens   = (const int*)d_in[2];
    const int*   label_lens = (const int*)d_in[3];

    float* ws       = (float*)d_ws;
    float* Aarr     = ws;                               // B*ND*WROW = 655360 f
    float* Barr     = Aarr + (size_t)BB * ND * WROW;    // B*ND*WROW = 655360 f
    float* p6arr    = Barr + (size_t)BB * ND * WROW;    // B*ND      =   5120 f
    float* bl64     = p6arr + BB * ND;                  // B*TM      =   4096 f
    float* partials = bl64 + BB * TM;                   // 32 f
    // total ~5.3 MB of ws

    const int nfill4 = (2 * BB * ND * WROW + BB * ND) / 4;  // Aarr+Barr+p6arr
    k_fill<<<(nfill4 + 255) / 256, 256, 0, stream>>>(ws, nfill4);

    const int rows = BB * TM * U1;
    k_lse<<<(rows + 3) / 4, 256, 0, stream>>>(acts, labels, Aarr, Barr, p6arr, bl64);
    k_dp<<<BB, 128, 0, stream>>>(Aarr, Barr, p6arr, bl64, act_lens, label_lens, partials);
    k_reduce<<<1, 64, 0, stream>>>(partials, (float*)d_out);
}

// Round 6
// 158.353 us; speedup vs baseline: 3.4593x; 1.1717x over previous
//
#include <hip/hip_runtime.h>
#include <hip/hip_bf16.h>

// Problem constants (from setup_inputs): B=16, Tm=256, U=64, V=512
#define BB   16
#define TM   256
#define UU   64
#define U1   65
#define VV   512
#define ND   320          // padded diagonal-row count (d = t+u in 0..318, +1 spare)
#define WROW 128          // interleaved row width (floats)
#define NEGF (-1e30f)
#define LOG2E 1.4426950408889634f
#define LN2   0.6931471805599453f

// Native 2^x / log2(x) (v_exp_f32 / v_log_f32), with portable fallback.
#if __has_builtin(__builtin_amdgcn_exp2f)
__device__ __forceinline__ float aexp2(float x) { return __builtin_amdgcn_exp2f(x); }
#else
__device__ __forceinline__ float aexp2(float x) { return exp2f(x); }
#endif
#if __has_builtin(__builtin_amdgcn_logf)
__device__ __forceinline__ float alog2(float x) { return __builtin_amdgcn_logf(x); }
#else
__device__ __forceinline__ float alog2(float x) { return log2f(x); }
#endif

// log-add-exp in base-2 log space (inputs pre-scaled by log2e).
__device__ __forceinline__ float lae2(float x, float y) {
    float m = fmaxf(x, y);
    return m + alog2(aexp2(x - m) + aexp2(y - m));
}
__device__ __forceinline__ float readlane_f(float v, int l) {
    return __int_as_float(__builtin_amdgcn_readlane(__float_as_int(v), l));
}
__device__ __forceinline__ float bperm_f(int addr, float v) {
    return __int_as_float(__builtin_amdgcn_ds_bpermute(addr, __float_as_int(v)));
}

// ---------------- Kernel 0: pad fill ----------------
// Aarr/Barr/p6arr pads must be NEGF every call (ws poisoned once, never again).
__global__ void k_fill(float* __restrict__ p, int n4) {
    int i = blockIdx.x * blockDim.x + threadIdx.x;
    if (i < n4) reinterpret_cast<float4*>(p)[i] = make_float4(NEGF, NEGF, NEGF, NEGF);
}

// ---------------- Kernel 1: log-softmax gather (sweep-specialized layout) ---
// One wave per (b,t,u) row of V=512 logits. All values pre-scaled by log2e.
// Alpha-step operands:  Aarr[b][r][2l+0] = blank(r-l,   l)
//                       Aarr[b][r][2l+1] = label(r-l+1, l-1)
// Beta-step operands:   Barr[b][r][2l+0] = label(r-l, l)
//                       Barr[b][r][2l+1] = blank(r-l, l)
// u=64-column scalars:  p6arr[b][r] = label(r-63, 63),  bl64[b][t] = blank(t,64)
__global__ __launch_bounds__(256) void k_lse(const float* __restrict__ acts,
                                             const int* __restrict__ labels,
                                             float* __restrict__ Aarr,
                                             float* __restrict__ Barr,
                                             float* __restrict__ p6arr,
                                             float* __restrict__ bl64) {
    int wid = (blockIdx.x << 2) + (threadIdx.x >> 6);
    if (wid >= BB * TM * U1) return;
    int lane = threadIdx.x & 63;
    const float* base = acts + (size_t)wid * VV;
    float4 va = *reinterpret_cast<const float4*>(base + lane * 4);
    float4 vb = *reinterpret_cast<const float4*>(base + 256 + lane * 4);
    float m = fmaxf(fmaxf(fmaxf(va.x, va.y), fmaxf(va.z, va.w)),
                    fmaxf(fmaxf(vb.x, vb.y), fmaxf(vb.z, vb.w)));
#pragma unroll
    for (int o = 32; o; o >>= 1) m = fmaxf(m, __shfl_xor(m, o));
    float s = __expf(va.x - m) + __expf(va.y - m) + __expf(va.z - m) + __expf(va.w - m)
            + __expf(vb.x - m) + __expf(vb.y - m) + __expf(vb.z - m) + __expf(vb.w - m);
#pragma unroll
    for (int o = 32; o; o >>= 1) s += __shfl_xor(s, o);
    float lse = m + __logf(s);
    if (lane == 0) {
        int u  = wid % U1;
        int bt = wid / U1;
        int t  = bt % TM;
        int b  = bt / TM;
        float blank = (va.x - lse) * LOG2E;       // index 0 = BLANK
        if (u < UU) {
            int r = t + u;
            int li = labels[b * UU + u];          // in [1, V)
            float lab = (base[li] - lse) * LOG2E;
            size_t row = ((size_t)b * ND + r) * WROW;
            *reinterpret_cast<float2*>(Barr + row + 2 * u) = make_float2(lab, blank);
            Aarr[row + 2 * u] = blank;
            if (u < 63) Aarr[row + 2 * u + 3] = lab;   // slot l=u+1
            else        p6arr[b * ND + r]     = lab;   // u=63 label feeds a64
        } else {
            bl64[b * TM + t] = blank;
        }
    }
}

// ---- chunk helpers: 8 diagonal steps per call, DS ops batched at edges ----
__device__ __forceinline__ void load8s(float2 (&B)[8], const float* base,
                                       int row0, int step, int lane) {
#pragma unroll
    for (int j = 0; j < 8; ++j)
        B[j] = *reinterpret_cast<const float2*>(base + (size_t)(row0 + j * step) * WROW + 2 * lane);
}

__device__ __forceinline__ void alpha_chunk(const float2 (&B)[8], int ss0,
    int lane, int up_addr, int ssCap, int ssCap64, int capLane,
    const float* __restrict__ s_bl64p, const float* __restrict__ s_p6,
    float* __restrict__ s_alpha,
    float& a, float& a64, float& aCapt, float& cap64)
{
    float c64r[8], p6r[8], aout[8];
#pragma unroll
    for (int j = 0; j < 8; ++j) {                 // uniform reads, batched
        int i64 = ss0 + j - 64; i64 = i64 < 0 ? 0 : i64;
        c64r[j] = s_bl64p[i64];
        p6r[j]  = s_p6[ss0 + j - 1];
    }
#pragma unroll
    for (int j = 0; j < 8; ++j) {
        const int ss = ss0 + j;
        const float left = bperm_f(up_addr, a);   // alpha[t, lane-1]
        const float a63u = readlane_f(a, 63);     // scalar pipe, off lgkm
        const float anew = lae2(a + B[j].x, left + B[j].y);
        a64 = lae2(a64 + c64r[j], a63u + p6r[j]); // uniform u=64 column
        a = anew;
        aout[j] = anew;
        if (ss == ssCap)   aCapt = readlane_f(a, capLane);   // uniform branch
        if (ss == ssCap64) cap64 = a64;                      // uniform branch
    }
#pragma unroll
    for (int j = 0; j < 8; ++j) {                 // stores, batched
        const int t = ss0 + j - lane;
        if ((unsigned)t < TM) s_alpha[t * UU + lane] = aout[j];
    }
}

__device__ __forceinline__ void beta_chunk(const float2 (&B)[8], int ss0,
    int lane, int dn_addr, int ssExit, int ssExit64, int L,
    const float* __restrict__ s_bl64p, float* __restrict__ s_pr,
    float& bt, float& b64)
{
    float c64r[8], bout[8];
#pragma unroll
    for (int j = 0; j < 8; ++j) {
        int i64 = ss0 - j - 63; i64 = i64 < 0 ? 0 : i64;
        c64r[j] = s_bl64p[i64];
    }
#pragma unroll
    for (int j = 0; j < 8; ++j) {
        const int ss = ss0 - j;
        float right = bperm_f(dn_addr, bt);       // beta[t, lane+1]
        right = (lane == 63) ? b64 : right;       // u=64 column neighbor
        const float pr = B[j].x + right;          // label + beta[t,u+1]
        float bnew = lae2(B[j].y + bt, pr);
        if (ss == ssExit) {                       // uniform branch, once/sweep
            if (lane == L) bnew = lae2(bnew, B[j].y);
        }
        float b64n = b64 + c64r[j];               // lae(x,-inf)=x
        if (ss == ssExit64) b64n = lae2(b64n, c64r[j]);  // L==64 exit
        b64 = b64n; bt = bnew; bout[j] = pr;
    }
#pragma unroll
    for (int j = 0; j < 8; ++j) {
        const int t = ss0 - j - lane;
        if ((unsigned)t < TM) s_pr[t * UU + lane] = bout[j];
    }
}

// ---------------- Kernel 2: concurrent fwd/bwd DP + fused delay ------------
// One block = 2 waves per example. Wave 0: alpha sweep; wave 1: beta sweep
// (stores s_pr[t][u] = label+beta[t,u+1]); then a joint gamma pass over LDS.
// 4 named 8-row register buffers, refilled per chunk (24-step lookahead).
__global__ __launch_bounds__(128, 1) void k_dp(const float* __restrict__ Aarr_,
                                               const float* __restrict__ Barr_,
                                               const float* __restrict__ p6arr_,
                                               const float* __restrict__ bl64_,
                                               const int* __restrict__ act_lens,
                                               const int* __restrict__ label_lens,
                                               float* __restrict__ partials) {
    __shared__ float s_alpha[TM * UU];            // 64 KB
    __shared__ float s_pr[TM * UU];               // 64 KB
    __shared__ float s_bl64p[TM + 2];             // [0]=pad, [1+t]=bl64[t]
    __shared__ float s_p6[ND];
    __shared__ float s_logZ;
    __shared__ float s_red[2];
    const int b    = blockIdx.x;
    const int tid  = threadIdx.x;
    const int lane = tid & 63;
    const int wv   = tid >> 6;
    const float* Aarr = Aarr_ + (size_t)b * ND * WROW;
    const float* Barr = Barr_ + (size_t)b * ND * WROW;

    if (tid == 0) { s_bl64p[0] = NEGF; s_bl64p[TM + 1] = NEGF; }
    for (int i = tid; i < TM; i += 128) s_bl64p[i + 1] = bl64_[b * TM + i];
    for (int i = tid; i < ND; i += 128) s_p6[i] = p6arr_[b * ND + i];
    __syncthreads();

    const int T = act_lens[b];
    const int L = label_lens[b];
    const int t_last = T - 1;

    if (wv == 0) {
        // ---- alpha sweep: ss = 1..320 (319,320 are harmless pad steps) ----
        float a = (lane == 0) ? 0.0f : NEGF;
        float a64 = NEGF, aCapt = NEGF, cap64 = NEGF;
        if (lane == 0) s_alpha[0] = 0.0f;
        const int up_addr = ((lane + 63) & 63) << 2;   // lane-1 (lane0 harmless)
        const int ssCap   = (L < UU) ? (t_last + L) : -1;
        const int ssCap64 = t_last + 64;
        float2 R0[8], R1[8], R2[8], R3[8];
        load8s(R0, Aarr, 0, 1, lane);  load8s(R1, Aarr, 8, 1, lane);
        load8s(R2, Aarr, 16, 1, lane); load8s(R3, Aarr, 24, 1, lane);
        for (int c = 0; c < 40; c += 4) {
            alpha_chunk(R0, c * 8 + 1, lane, up_addr, ssCap, ssCap64, L,
                        s_bl64p, s_p6, s_alpha, a, a64, aCapt, cap64);
            if (c < 36) load8s(R0, Aarr, (c + 4) * 8, 1, lane);
            alpha_chunk(R1, (c + 1) * 8 + 1, lane, up_addr, ssCap, ssCap64, L,
                        s_bl64p, s_p6, s_alpha, a, a64, aCapt, cap64);
            if (c < 36) load8s(R1, Aarr, (c + 5) * 8, 1, lane);
            alpha_chunk(R2, (c + 2) * 8 + 1, lane, up_addr, ssCap, ssCap64, L,
                        s_bl64p, s_p6, s_alpha, a, a64, aCapt, cap64);
            if (c < 36) load8s(R2, Aarr, (c + 6) * 8, 1, lane);
            alpha_chunk(R3, (c + 3) * 8 + 1, lane, up_addr, ssCap, ssCap64, L,
                        s_bl64p, s_p6, s_alpha, a, a64, aCapt, cap64);
            if (c < 36) load8s(R3, Aarr, (c + 7) * 8, 1, lane);
        }
        const float aE = (L < UU) ? aCapt : cap64;
        const float blankLast = (L < UU) ? Aarr[(size_t)(t_last + L) * WROW + 2 * L]
                                         : s_bl64p[t_last + 1];
        if (lane == 0) s_logZ = aE + blankLast;   // base-2 units
    } else {
        // ---- beta sweep: ss = 319..0 ----
        float bt = NEGF, b64 = NEGF;
        const int dn_addr  = ((lane + 1) & 63) << 2;   // lane+1 (lane63 patched)
        const int ssExit   = t_last + L;               // lane==L only if L<64
        const int ssExit64 = (L == UU) ? (t_last + 64) : -1;
        float2 R0[8], R1[8], R2[8], R3[8];
        load8s(R0, Barr, 319, -1, lane); load8s(R1, Barr, 311, -1, lane);
        load8s(R2, Barr, 303, -1, lane); load8s(R3, Barr, 295, -1, lane);
        for (int c = 0; c < 40; c += 4) {
            beta_chunk(R0, 319 - c * 8, lane, dn_addr, ssExit, ssExit64, L,
                       s_bl64p, s_pr, bt, b64);
            if (c < 36) load8s(R0, Barr, 319 - (c + 4) * 8, -1, lane);
            beta_chunk(R1, 319 - (c + 1) * 8, lane, dn_addr, ssExit, ssExit64, L,
                       s_bl64p, s_pr, bt, b64);
            if (c < 36) load8s(R1, Barr, 319 - (c + 5) * 8, -1, lane);
            beta_chunk(R2, 319 - (c + 2) * 8, lane, dn_addr, ssExit, ssExit64, L,
                       s_bl64p, s_pr, bt, b64);
            if (c < 36) load8s(R2, Barr, 319 - (c + 6) * 8, -1, lane);
            beta_chunk(R3, 319 - (c + 3) * 8, lane, dn_addr, ssExit, ssExit64, L,
                       s_bl64p, s_pr, bt, b64);
            if (c < 36) load8s(R3, Barr, 319 - (c + 7) * 8, -1, lane);
        }
    }
    __syncthreads();

    // ---- gamma pass: dsum = sum exp2(alpha + pr - logZ) * t/T ----
    const float logZ = s_logZ;
    const float invT = 1.0f / (float)T;
    float dsum = 0.0f;
#pragma unroll 8
    for (int idx = tid; idx < TM * UU; idx += 128) {
        const int t = idx >> 6;
        dsum = __fmaf_rn(aexp2(s_alpha[idx] + s_pr[idx] - logZ),
                         (float)t * invT, dsum);
    }
#pragma unroll
    for (int o = 32; o; o >>= 1) dsum += __shfl_xor(dsum, o);
    if (lane == 0) s_red[wv] = dsum;
    __syncthreads();
    if (tid == 0) {
        partials[2 * b + 0] = -logZ * LN2;        // loss_rnnt_b (nat units)
        partials[2 * b + 1] = s_red[0] + s_red[1];
    }
}

// ---------------- Kernel 3: final reduction ----------------
__global__ void k_reduce(const float* __restrict__ partials, float* __restrict__ out) {
    if (threadIdx.x == 0 && blockIdx.x == 0) {
        float rn = 0.0f, dl = 0.0f;
        for (int b = 0; b < BB; ++b) {
            rn += partials[2 * b + 0];
            dl += partials[2 * b + 1];
        }
        out[0] = rn + dl;   // loss_total  (DELAY_SCALE = 1)
        out[1] = rn;        // loss_rnnt
        out[2] = dl;        // loss_delay
    }
}

extern "C" void kernel_launch(void* const* d_in, const int* in_sizes, int n_in,
                              void* d_out, int out_size, void* d_ws, size_t ws_size,
                              hipStream_t stream) {
    const float* acts       = (const float*)d_in[0];
    const int*   labels     = (const int*)d_in[1];
    const int*   act_lens   = (const int*)d_in[2];
    const int*   label_lens = (const int*)d_in[3];

    float* ws       = (float*)d_ws;
    float* Aarr     = ws;                               // B*ND*WROW = 655360 f
    float* Barr     = Aarr + (size_t)BB * ND * WROW;    // B*ND*WROW = 655360 f
    float* p6arr    = Barr + (size_t)BB * ND * WROW;    // B*ND      =   5120 f
    float* bl64     = p6arr + BB * ND;                  // B*TM      =   4096 f
    float* partials = bl64 + BB * TM;                   // 32 f
    // total ~5.3 MB of ws

    const int nfill4 = (2 * BB * ND * WROW + BB * ND) / 4;  // Aarr+Barr+p6arr
    k_fill<<<(nfill4 + 255) / 256, 256, 0, stream>>>(ws, nfill4);

    const int rows = BB * TM * U1;
    k_lse<<<(rows + 3) / 4, 256, 0, stream>>>(acts, labels, Aarr, Barr, p6arr, bl64);
    k_dp<<<BB, 128, 0, stream>>>(Aarr, Barr, p6arr, bl64, act_lens, label_lens, partials);
    k_reduce<<<1, 64, 0, stream>>>(partials, (float*)d_out);
}

// Round 7
// 153.223 us; speedup vs baseline: 3.5751x; 1.0335x over previous
//
#include <hip/hip_runtime.h>
#include <hip/hip_bf16.h>

// Problem constants (from setup_inputs): B=16, Tm=256, U=64, V=512
#define BB   16
#define TM   256
#define UU   64
#define U1   65
#define VV   512
#define ND   320          // padded diagonal-row count (d = t+u in 0..318, +1 spare)
#define WROW 128          // interleaved row width (floats)
#define NEGF (-1e30f)
#define LOG2E 1.4426950408889634f
#define LN2   0.6931471805599453f

// Native 2^x / log2(x) (v_exp_f32 / v_log_f32), with portable fallback.
#if __has_builtin(__builtin_amdgcn_exp2f)
__device__ __forceinline__ float aexp2(float x) { return __builtin_amdgcn_exp2f(x); }
#else
__device__ __forceinline__ float aexp2(float x) { return exp2f(x); }
#endif
#if __has_builtin(__builtin_amdgcn_logf)
__device__ __forceinline__ float alog2(float x) { return __builtin_amdgcn_logf(x); }
#else
__device__ __forceinline__ float alog2(float x) { return log2f(x); }
#endif

// log-add-exp, base-2 log space: max + log2(1 + exp2(-|x-y|)) — 2 trans ops.
__device__ __forceinline__ float lae2(float x, float y) {
    float m = fmaxf(x, y);
    return m + alog2(1.0f + aexp2(-fabsf(x - y)));
}
__device__ __forceinline__ float readlane_f(float v, int l) {
    return __int_as_float(__builtin_amdgcn_readlane(__float_as_int(v), l));
}
// Whole-wave shift via DPP (gfx9-lineage keeps wave_shr/wave_shl).
// Invalid boundary lane keeps old (=v); pads/cndmask neutralize it.
__device__ __forceinline__ float shfl_up1(float v) {   // lane i <- lane i-1
    return __int_as_float(__builtin_amdgcn_update_dpp(
        __float_as_int(v), __float_as_int(v), 0x138, 0xF, 0xF, false));
}
__device__ __forceinline__ float shfl_dn1(float v) {   // lane i <- lane i+1
    return __int_as_float(__builtin_amdgcn_update_dpp(
        __float_as_int(v), __float_as_int(v), 0x130, 0xF, 0xF, false));
}

// ---------------- Kernel 0: pad fill ----------------
// Aarr/Barr/p6arr pads must be NEGF every call (ws poisoned once, never again).
__global__ void k_fill(float* __restrict__ p, int n4) {
    int i = blockIdx.x * blockDim.x + threadIdx.x;
    if (i < n4) reinterpret_cast<float4*>(p)[i] = make_float4(NEGF, NEGF, NEGF, NEGF);
}

// ---------------- Kernel 1: log-softmax gather (sweep-specialized layout) ---
// One wave per (b,t,u) row of V=512 logits. All values pre-scaled by log2e.
// Alpha-step operands:  Aarr[b][r][2l+0] = blank(r-l,   l)
//                       Aarr[b][r][2l+1] = label(r-l+1, l-1)
// Beta-step operands:   Barr[b][r][2l+0] = label(r-l, l)
//                       Barr[b][r][2l+1] = blank(r-l, l)
// u=64-column scalars:  p6arr[b][r] = label(r-63, 63),  bl64[b][t] = blank(t,64)
__global__ __launch_bounds__(256) void k_lse(const float* __restrict__ acts,
                                             const int* __restrict__ labels,
                                             float* __restrict__ Aarr,
                                             float* __restrict__ Barr,
                                             float* __restrict__ p6arr,
                                             float* __restrict__ bl64) {
    int wid = (blockIdx.x << 2) + (threadIdx.x >> 6);
    if (wid >= BB * TM * U1) return;
    int lane = threadIdx.x & 63;
    const float* base = acts + (size_t)wid * VV;
    float4 va = *reinterpret_cast<const float4*>(base + lane * 4);
    float4 vb = *reinterpret_cast<const float4*>(base + 256 + lane * 4);
    float m = fmaxf(fmaxf(fmaxf(va.x, va.y), fmaxf(va.z, va.w)),
                    fmaxf(fmaxf(vb.x, vb.y), fmaxf(vb.z, vb.w)));
#pragma unroll
    for (int o = 32; o; o >>= 1) m = fmaxf(m, __shfl_xor(m, o));
    float s = __expf(va.x - m) + __expf(va.y - m) + __expf(va.z - m) + __expf(va.w - m)
            + __expf(vb.x - m) + __expf(vb.y - m) + __expf(vb.z - m) + __expf(vb.w - m);
#pragma unroll
    for (int o = 32; o; o >>= 1) s += __shfl_xor(s, o);
    float lse = m + __logf(s);
    if (lane == 0) {
        int u  = wid % U1;
        int bt = wid / U1;
        int t  = bt % TM;
        int b  = bt / TM;
        float blank = (va.x - lse) * LOG2E;       // index 0 = BLANK
        if (u < UU) {
            int r = t + u;
            int li = labels[b * UU + u];          // in [1, V)
            float lab = (base[li] - lse) * LOG2E;
            size_t row = ((size_t)b * ND + r) * WROW;
            *reinterpret_cast<float2*>(Barr + row + 2 * u) = make_float2(lab, blank);
            Aarr[row + 2 * u] = blank;
            if (u < 63) Aarr[row + 2 * u + 3] = lab;   // slot l=u+1
            else        p6arr[b * ND + r]     = lab;   // u=63 label feeds a64
        } else {
            bl64[b * TM + t] = blank;
        }
    }
}

// ---- chunk helpers: 8 diagonal steps per call, DS ops batched at edges ----
__device__ __forceinline__ void load8s(float2 (&B)[8], const float* base,
                                       int row0, int step, int lane) {
#pragma unroll
    for (int j = 0; j < 8; ++j)
        B[j] = *reinterpret_cast<const float2*>(base + (size_t)(row0 + j * step) * WROW + 2 * lane);
}

template<bool N64>
__device__ __forceinline__ void alpha_chunk(const float2 (&B)[8], int ss0,
    int lane, int ssCap, int ssCap64, int capLane,
    const float* __restrict__ s_bl64p, const float* __restrict__ s_p6,
    float* __restrict__ s_alpha,
    float& a, float& a64, float& aCapt, float& cap64)
{
    float c64r[8], p6r[8], aout[8];
    if (N64) {
#pragma unroll
        for (int j = 0; j < 8; ++j) {             // uniform reads, batched
            int i64 = ss0 + j - 64; i64 = i64 < 0 ? 0 : i64;
            c64r[j] = s_bl64p[i64];
            p6r[j]  = s_p6[ss0 + j - 1];
        }
    }
#pragma unroll
    for (int j = 0; j < 8; ++j) {
        const int ss = ss0 + j;
        const float left = shfl_up1(a);           // alpha[t, lane-1] (DPP)
        const float anew = lae2(a + B[j].x, left + B[j].y);
        if (N64) {
            const float a63u = readlane_f(a, 63); // alpha[t64, 63]
            a64 = lae2(a64 + c64r[j], a63u + p6r[j]);
            if (ss == ssCap64) cap64 = a64;
        }
        a = anew;
        aout[j] = anew;
        if (!N64 && ss == ssCap) aCapt = readlane_f(a, capLane);  // uniform
    }
#pragma unroll
    for (int j = 0; j < 8; ++j) {                 // stores, batched
        const int t = ss0 + j - lane;
        if ((unsigned)t < TM) s_alpha[t * UU + lane] = aout[j];
    }
}

__device__ __forceinline__ void beta_chunk(const float2 (&B)[8], int ss0,
    int lane, int ssExit, int ssExit64, int L,
    const float* __restrict__ s_bl64p, float* __restrict__ s_pr,
    float& bt, float& b64)
{
    float c64r[8], bout[8];
#pragma unroll
    for (int j = 0; j < 8; ++j) {
        int i64 = ss0 - j - 63; i64 = i64 < 0 ? 0 : i64;
        c64r[j] = s_bl64p[i64];
    }
#pragma unroll
    for (int j = 0; j < 8; ++j) {
        const int ss = ss0 - j;
        float right = shfl_dn1(bt);               // beta[t, lane+1] (DPP)
        right = (lane == 63) ? b64 : right;       // u=64 column neighbor
        const float pr = B[j].x + right;          // label + beta[t,u+1]
        float bnew = lae2(B[j].y + bt, pr);
        if (ss == ssExit) {                       // uniform branch, once/sweep
            if (lane == L) bnew = lae2(bnew, B[j].y);
        }
        float b64n = b64 + c64r[j];               // lae(x,-inf)=x
        if (ss == ssExit64) b64n = lae2(b64n, c64r[j]);  // L==64 exit
        b64 = b64n; bt = bnew; bout[j] = pr;
    }
#pragma unroll
    for (int j = 0; j < 8; ++j) {
        const int t = ss0 - j - lane;
        if ((unsigned)t < TM) s_pr[t * UU + lane] = bout[j];
    }
}

template<bool N64>
__device__ __forceinline__ float alpha_sweep(const float* __restrict__ Aarr,
    int lane, int t_last, int L,
    const float* __restrict__ s_bl64p, const float* __restrict__ s_p6,
    float* __restrict__ s_alpha)
{
    float a = (lane == 0) ? 0.0f : NEGF;
    float a64 = NEGF, aCapt = NEGF, cap64 = NEGF;
    if (lane == 0) s_alpha[0] = 0.0f;
    const int ssCap   = N64 ? -1 : (t_last + L);
    const int ssCap64 = t_last + 64;
    float2 R0[8], R1[8], R2[8], R3[8];
    load8s(R0, Aarr, 0, 1, lane);  load8s(R1, Aarr, 8, 1, lane);
    load8s(R2, Aarr, 16, 1, lane); load8s(R3, Aarr, 24, 1, lane);
    for (int c = 0; c < 40; c += 4) {
        alpha_chunk<N64>(R0, c * 8 + 1, lane, ssCap, ssCap64, L,
                         s_bl64p, s_p6, s_alpha, a, a64, aCapt, cap64);
        if (c < 36) load8s(R0, Aarr, (c + 4) * 8, 1, lane);
        alpha_chunk<N64>(R1, (c + 1) * 8 + 1, lane, ssCap, ssCap64, L,
                         s_bl64p, s_p6, s_alpha, a, a64, aCapt, cap64);
        if (c < 36) load8s(R1, Aarr, (c + 5) * 8, 1, lane);
        alpha_chunk<N64>(R2, (c + 2) * 8 + 1, lane, ssCap, ssCap64, L,
                         s_bl64p, s_p6, s_alpha, a, a64, aCapt, cap64);
        if (c < 36) load8s(R2, Aarr, (c + 6) * 8, 1, lane);
        alpha_chunk<N64>(R3, (c + 3) * 8 + 1, lane, ssCap, ssCap64, L,
                         s_bl64p, s_p6, s_alpha, a, a64, aCapt, cap64);
        if (c < 36) load8s(R3, Aarr, (c + 7) * 8, 1, lane);
    }
    return N64 ? cap64 : aCapt;
}

// ---------------- Kernel 2: concurrent fwd/bwd DP + fused delay ------------
// One block = 2 waves per example. Wave 0: alpha sweep; wave 1: beta sweep
// (stores s_pr[t][u] = label+beta[t,u+1]); then a joint gamma pass over LDS.
__global__ __launch_bounds__(128, 1) void k_dp(const float* __restrict__ Aarr_,
                                               const float* __restrict__ Barr_,
                                               const float* __restrict__ p6arr_,
                                               const float* __restrict__ bl64_,
                                               const int* __restrict__ act_lens,
                                               const int* __restrict__ label_lens,
                                               float* __restrict__ partials) {
    __shared__ float s_alpha[TM * UU];            // 64 KB
    __shared__ float s_pr[TM * UU];               // 64 KB
    __shared__ float s_bl64p[TM + 2];             // [0]=pad, [1+t]=bl64[t]
    __shared__ float s_p6[ND];
    __shared__ float s_logZ;
    __shared__ float s_red[2];
    const int b    = blockIdx.x;
    const int tid  = threadIdx.x;
    const int lane = tid & 63;
    const int wv   = tid >> 6;
    const float* Aarr = Aarr_ + (size_t)b * ND * WROW;
    const float* Barr = Barr_ + (size_t)b * ND * WROW;

    if (tid == 0) { s_bl64p[0] = NEGF; s_bl64p[TM + 1] = NEGF; }
    for (int i = tid; i < TM; i += 128) s_bl64p[i + 1] = bl64_[b * TM + i];
    for (int i = tid; i < ND; i += 128) s_p6[i] = p6arr_[b * ND + i];
    __syncthreads();

    const int T = act_lens[b];
    const int L = label_lens[b];
    const int t_last = T - 1;

    if (wv == 0) {
        const float aE = (L == UU)
            ? alpha_sweep<true >(Aarr, lane, t_last, L, s_bl64p, s_p6, s_alpha)
            : alpha_sweep<false>(Aarr, lane, t_last, L, s_bl64p, s_p6, s_alpha);
        const float blankLast = (L < UU) ? Aarr[(size_t)(t_last + L) * WROW + 2 * L]
                                         : s_bl64p[t_last + 1];
        if (lane == 0) s_logZ = aE + blankLast;   // base-2 units
    } else {
        // ---- beta sweep: ss = 319..0 ----
        float bt = NEGF, b64 = NEGF;
        const int ssExit   = t_last + L;               // lane==L only if L<64
        const int ssExit64 = (L == UU) ? (t_last + 64) : -1;
        float2 R0[8], R1[8], R2[8], R3[8];
        load8s(R0, Barr, 319, -1, lane); load8s(R1, Barr, 311, -1, lane);
        load8s(R2, Barr, 303, -1, lane); load8s(R3, Barr, 295, -1, lane);
        for (int c = 0; c < 40; c += 4) {
            beta_chunk(R0, 319 - c * 8, lane, ssExit, ssExit64, L,
                       s_bl64p, s_pr, bt, b64);
            if (c < 36) load8s(R0, Barr, 319 - (c + 4) * 8, -1, lane);
            beta_chunk(R1, 319 - (c + 1) * 8, lane, ssExit, ssExit64, L,
                       s_bl64p, s_pr, bt, b64);
            if (c < 36) load8s(R1, Barr, 319 - (c + 5) * 8, -1, lane);
            beta_chunk(R2, 319 - (c + 2) * 8, lane, ssExit, ssExit64, L,
                       s_bl64p, s_pr, bt, b64);
            if (c < 36) load8s(R2, Barr, 319 - (c + 6) * 8, -1, lane);
            beta_chunk(R3, 319 - (c + 3) * 8, lane, ssExit, ssExit64, L,
                       s_bl64p, s_pr, bt, b64);
            if (c < 36) load8s(R3, Barr, 319 - (c + 7) * 8, -1, lane);
        }
    }
    __syncthreads();

    // ---- gamma pass: dsum = sum exp2(alpha + pr - logZ) * t/T ----
    const float logZ = s_logZ;
    const float invT = 1.0f / (float)T;
    float dsum = 0.0f;
#pragma unroll 8
    for (int idx = tid; idx < TM * UU; idx += 128) {
        const int t = idx >> 6;
        dsum = __fmaf_rn(aexp2(s_alpha[idx] + s_pr[idx] - logZ),
                         (float)t * invT, dsum);
    }
#pragma unroll
    for (int o = 32; o; o >>= 1) dsum += __shfl_xor(dsum, o);
    if (lane == 0) s_red[wv] = dsum;
    __syncthreads();
    if (tid == 0) {
        partials[2 * b + 0] = -logZ * LN2;        // loss_rnnt_b (nat units)
        partials[2 * b + 1] = s_red[0] + s_red[1];
    }
}

// ---------------- Kernel 3: final reduction ----------------
__global__ void k_reduce(const float* __restrict__ partials, float* __restrict__ out) {
    if (threadIdx.x == 0 && blockIdx.x == 0) {
        float rn = 0.0f, dl = 0.0f;
        for (int b = 0; b < BB; ++b) {
            rn += partials[2 * b + 0];
            dl += partials[2 * b + 1];
        }
        out[0] = rn + dl;   // loss_total  (DELAY_SCALE = 1)
        out[1] = rn;        // loss_rnnt
        out[2] = dl;        // loss_delay
    }
}

extern "C" void kernel_launch(void* const* d_in, const int* in_sizes, int n_in,
                              void* d_out, int out_size, void* d_ws, size_t ws_size,
                              hipStream_t stream) {
    const float* acts       = (const float*)d_in[0];
    const int*   labels     = (const int*)d_in[1];
    const int*   act_lens   = (const int*)d_in[2];
    const int*   label_lens = (const int*)d_in[3];

    float* ws       = (float*)d_ws;
    float* Aarr     = ws;                               // B*ND*WROW = 655360 f
    float* Barr     = Aarr + (size_t)BB * ND * WROW;    // B*ND*WROW = 655360 f
    float* p6arr    = Barr + (size_t)BB * ND * WROW;    // B*ND      =   5120 f
    float* bl64     = p6arr + BB * ND;                  // B*TM      =   4096 f
    float* partials = bl64 + BB * TM;                   // 32 f
    // total ~5.3 MB of ws

    const int nfill4 = (2 * BB * ND * WROW + BB * ND) / 4;  // Aarr+Barr+p6arr
    k_fill<<<(nfill4 + 255) / 256, 256, 0, stream>>>(ws, nfill4);

    const int rows = BB * TM * U1;
    k_lse<<<(rows + 3) / 4, 256, 0, stream>>>(acts, labels, Aarr, Barr, p6arr, bl64);
    k_dp<<<BB, 128, 0, stream>>>(Aarr, Barr, p6arr, bl64, act_lens, label_lens, partials);
    k_reduce<<<1, 64, 0, stream>>>(partials, (float*)d_out);
}

// Round 8
// 140.843 us; speedup vs baseline: 3.8893x; 1.0879x over previous
//
#include <hip/hip_runtime.h>
#include <hip/hip_bf16.h>

// Problem constants (from setup_inputs): B=16, Tm=256, U=64, V=512
#define BB   16
#define TM   256
#define UU   64
#define U1   65
#define VV   512
#define ND   320          // padded diagonal-row count (d = t+u in 0..318, +1 spare)
#define WROW 128          // interleaved row width (floats)
#define NEGF (-1e30f)
#define LOG2E 1.4426950408889634f
#define LN2   0.6931471805599453f

// Native 2^x / log2(x) (v_exp_f32 / v_log_f32), with portable fallback.
#if __has_builtin(__builtin_amdgcn_exp2f)
__device__ __forceinline__ float aexp2(float x) { return __builtin_amdgcn_exp2f(x); }
#else
__device__ __forceinline__ float aexp2(float x) { return exp2f(x); }
#endif
#if __has_builtin(__builtin_amdgcn_logf)
__device__ __forceinline__ float alog2(float x) { return __builtin_amdgcn_logf(x); }
#else
__device__ __forceinline__ float alog2(float x) { return log2f(x); }
#endif

// log-add-exp, base-2 log space: max + log2(1 + exp2(-|x-y|)) — 2 trans ops.
__device__ __forceinline__ float lae2(float x, float y) {
    float m = fmaxf(x, y);
    return m + alog2(1.0f + aexp2(-fabsf(x - y)));
}
__device__ __forceinline__ float readlane_f(float v, int l) {
    return __int_as_float(__builtin_amdgcn_readlane(__float_as_int(v), l));
}
// Whole-wave shift via DPP (gfx9-lineage wave_shr/wave_shl).
// Invalid boundary lane keeps old (=v); pads/cndmask neutralize it.
__device__ __forceinline__ float shfl_up1(float v) {   // lane i <- lane i-1
    return __int_as_float(__builtin_amdgcn_update_dpp(
        __float_as_int(v), __float_as_int(v), 0x138, 0xF, 0xF, false));
}
__device__ __forceinline__ float shfl_dn1(float v) {   // lane i <- lane i+1
    return __int_as_float(__builtin_amdgcn_update_dpp(
        __float_as_int(v), __float_as_int(v), 0x130, 0xF, 0xF, false));
}
// Unguarded LDS store with clamped row: t<-1 -> trash row 0, t>256 -> row 257.
__device__ __forceinline__ void st_clamped(float* __restrict__ s, int t, int lane, float v) {
    int tc = t < -1 ? -1 : t;                     // min/max -> v_med3_i32
    tc = tc > 256 ? 256 : tc;
    s[(tc + 1) * UU + lane] = v;
}

// ---------------- Kernel 0: pad fill ----------------
// Aarr/Barr/p6arr pads must be NEGF every call (ws poisoned once, never again).
__global__ void k_fill(float* __restrict__ p, int n4) {
    int i = blockIdx.x * blockDim.x + threadIdx.x;
    if (i < n4) reinterpret_cast<float4*>(p)[i] = make_float4(NEGF, NEGF, NEGF, NEGF);
}

// ---------------- Kernel 1: log-softmax gather (sweep-specialized layout) ---
// One wave per (b,t,u) row of V=512 logits. All values pre-scaled by log2e.
// Alpha-step operands:  Aarr[b][r][2l+0] = blank(r-l,   l)
//                       Aarr[b][r][2l+1] = label(r-l+1, l-1)
// Beta-step operands:   Barr[b][r][2l+0] = label(r-l, l)
//                       Barr[b][r][2l+1] = blank(r-l, l)
// u=64-column scalars:  p6arr[b][r] = label(r-63, 63),  bl64[b][t] = blank(t,64)
__global__ __launch_bounds__(256) void k_lse(const float* __restrict__ acts,
                                             const int* __restrict__ labels,
                                             float* __restrict__ Aarr,
                                             float* __restrict__ Barr,
                                             float* __restrict__ p6arr,
                                             float* __restrict__ bl64) {
    int wid = (blockIdx.x << 2) + (threadIdx.x >> 6);
    if (wid >= BB * TM * U1) return;
    int lane = threadIdx.x & 63;
    const float* base = acts + (size_t)wid * VV;
    float4 va = *reinterpret_cast<const float4*>(base + lane * 4);
    float4 vb = *reinterpret_cast<const float4*>(base + 256 + lane * 4);
    float m = fmaxf(fmaxf(fmaxf(va.x, va.y), fmaxf(va.z, va.w)),
                    fmaxf(fmaxf(vb.x, vb.y), fmaxf(vb.z, vb.w)));
#pragma unroll
    for (int o = 32; o; o >>= 1) m = fmaxf(m, __shfl_xor(m, o));
    float s = __expf(va.x - m) + __expf(va.y - m) + __expf(va.z - m) + __expf(va.w - m)
            + __expf(vb.x - m) + __expf(vb.y - m) + __expf(vb.z - m) + __expf(vb.w - m);
#pragma unroll
    for (int o = 32; o; o >>= 1) s += __shfl_xor(s, o);
    float lse = m + __logf(s);
    if (lane == 0) {
        int u  = wid % U1;
        int bt = wid / U1;
        int t  = bt % TM;
        int b  = bt / TM;
        float blank = (va.x - lse) * LOG2E;       // index 0 = BLANK
        if (u < UU) {
            int r = t + u;
            int li = labels[b * UU + u];          // in [1, V)
            float lab = (base[li] - lse) * LOG2E;
            size_t row = ((size_t)b * ND + r) * WROW;
            *reinterpret_cast<float2*>(Barr + row + 2 * u) = make_float2(lab, blank);
            Aarr[row + 2 * u] = blank;
            if (u < 63) Aarr[row + 2 * u + 3] = lab;   // slot l=u+1
            else        p6arr[b * ND + r]     = lab;   // u=63 label feeds a64
        } else {
            bl64[b * TM + t] = blank;
        }
    }
}

// ---- chunk helpers: 8 diagonal steps per call ----
__device__ __forceinline__ void load8s(float2 (&B)[8], const float* base,
                                       int row0, int step, int lane) {
#pragma unroll
    for (int j = 0; j < 8; ++j)
        B[j] = *reinterpret_cast<const float2*>(base + (size_t)(row0 + j * step) * WROW + 2 * lane);
}

template<bool N64>
__device__ __forceinline__ void alpha_chunk(const float2 (&B)[8], int ss0,
    int lane, int ssCap64,
    const float* __restrict__ s_bl64p, const float* __restrict__ s_p6,
    float* __restrict__ s_alpha,
    float& a, float& a64, float& cap64)
{
    float c64r[8], p6r[8], aout[8];
    if (N64) {
#pragma unroll
        for (int j = 0; j < 8; ++j) {             // uniform reads, batched
            int i64 = ss0 + j - 64; i64 = i64 < 0 ? 0 : i64;
            c64r[j] = s_bl64p[i64];
            p6r[j]  = s_p6[ss0 + j - 1];
        }
    }
#pragma unroll
    for (int j = 0; j < 8; ++j) {
        const float left = shfl_up1(a);           // alpha[t, lane-1] (DPP)
        const float anew = lae2(a + B[j].x, left + B[j].y);
        if (N64) {
            const float a63u = readlane_f(a, 63); // old a: alpha[t64, 63]
            a64 = lae2(a64 + c64r[j], a63u + p6r[j]);
            if (ss0 + j == ssCap64) cap64 = a64;
        }
        a = anew;
        aout[j] = anew;
    }
#pragma unroll
    for (int j = 0; j < 8; ++j)                   // unguarded clamped stores
        st_clamped(s_alpha, ss0 + j - lane, lane, aout[j]);
}

template<bool N64>
__device__ __forceinline__ void beta_chunk(const float2 (&B)[8], int ss0,
    int lane, int ssExit, int ssExit64, int L,
    const float* __restrict__ s_bl64p, float* __restrict__ s_pr,
    float& bt, float& b64)
{
    float c64r[8], bout[8];
    if (N64) {
#pragma unroll
        for (int j = 0; j < 8; ++j) {
            int i64 = ss0 - j - 63; i64 = i64 < 0 ? 0 : i64;
            c64r[j] = s_bl64p[i64];
        }
    }
#pragma unroll
    for (int j = 0; j < 8; ++j) {
        const int ss = ss0 - j;
        float right = shfl_dn1(bt);               // beta[t, lane+1] (DPP)
        right = (lane == 63) ? (N64 ? b64 : NEGF) : right;  // u=64 neighbor
        const float pr = B[j].x + right;          // label + beta[t,u+1]
        float bnew = lae2(B[j].y + bt, pr);
        if (ss == ssExit) {                       // uniform branch
            if (lane == L) bnew = lae2(bnew, B[j].y);
        }
        if (N64) {
            float b64n = b64 + c64r[j];           // lae(x,-inf)=x
            if (ss == ssExit64) b64n = lae2(b64n, c64r[j]);
            b64 = b64n;
        }
        bt = bnew; bout[j] = pr;
    }
#pragma unroll
    for (int j = 0; j < 8; ++j)
        st_clamped(s_pr, ss0 - j - lane, lane, bout[j]);
}

template<bool N64>
__device__ __forceinline__ float alpha_sweep(const float* __restrict__ Aarr,
    int lane, int t_last, int L,
    const float* __restrict__ s_bl64p, const float* __restrict__ s_p6,
    float* __restrict__ s_alpha)
{
    float a = (lane == 0) ? 0.0f : NEGF;
    float a64 = NEGF, cap64 = NEGF;
    const int ssCap64 = t_last + 64;
    float2 R0[8], R1[8], R2[8], R3[8], R4[8];
    load8s(R0, Aarr, 0, 1, lane);  load8s(R1, Aarr, 8, 1, lane);
    load8s(R2, Aarr, 16, 1, lane); load8s(R3, Aarr, 24, 1, lane);
    load8s(R4, Aarr, 32, 1, lane);
    for (int c = 0; c < 40; c += 5) {             // chunk i consumes rows i*8..i*8+7
        alpha_chunk<N64>(R0, c * 8 + 1, lane, ssCap64, s_bl64p, s_p6, s_alpha, a, a64, cap64);
        if (c + 5 < 40) load8s(R0, Aarr, (c + 5) * 8, 1, lane);
        alpha_chunk<N64>(R1, (c + 1) * 8 + 1, lane, ssCap64, s_bl64p, s_p6, s_alpha, a, a64, cap64);
        if (c + 6 < 40) load8s(R1, Aarr, (c + 6) * 8, 1, lane);
        alpha_chunk<N64>(R2, (c + 2) * 8 + 1, lane, ssCap64, s_bl64p, s_p6, s_alpha, a, a64, cap64);
        if (c + 7 < 40) load8s(R2, Aarr, (c + 7) * 8, 1, lane);
        alpha_chunk<N64>(R3, (c + 3) * 8 + 1, lane, ssCap64, s_bl64p, s_p6, s_alpha, a, a64, cap64);
        if (c + 8 < 40) load8s(R3, Aarr, (c + 8) * 8, 1, lane);
        alpha_chunk<N64>(R4, (c + 4) * 8 + 1, lane, ssCap64, s_bl64p, s_p6, s_alpha, a, a64, cap64);
        if (c + 9 < 40) load8s(R4, Aarr, (c + 9) * 8, 1, lane);
    }
    return cap64;                                 // meaningful only for N64
}

template<bool N64>
__device__ __forceinline__ void beta_sweep(const float* __restrict__ Barr,
    int lane, int ssExit, int ssExit64, int L,
    const float* __restrict__ s_bl64p, float* __restrict__ s_pr)
{
    float bt = NEGF, b64 = NEGF;
    float2 R0[8], R1[8], R2[8], R3[8], R4[8];
    load8s(R0, Barr, 319, -1, lane); load8s(R1, Barr, 311, -1, lane);
    load8s(R2, Barr, 303, -1, lane); load8s(R3, Barr, 295, -1, lane);
    load8s(R4, Barr, 287, -1, lane);
    for (int c = 0; c < 40; c += 5) {             // chunk i consumes rows 319-i*8 ..
        beta_chunk<N64>(R0, 319 - c * 8, lane, ssExit, ssExit64, L, s_bl64p, s_pr, bt, b64);
        if (c + 5 < 40) load8s(R0, Barr, 319 - (c + 5) * 8, -1, lane);
        beta_chunk<N64>(R1, 319 - (c + 1) * 8, lane, ssExit, ssExit64, L, s_bl64p, s_pr, bt, b64);
        if (c + 6 < 40) load8s(R1, Barr, 319 - (c + 6) * 8, -1, lane);
        beta_chunk<N64>(R2, 319 - (c + 2) * 8, lane, ssExit, ssExit64, L, s_bl64p, s_pr, bt, b64);
        if (c + 7 < 40) load8s(R2, Barr, 319 - (c + 7) * 8, -1, lane);
        beta_chunk<N64>(R3, 319 - (c + 3) * 8, lane, ssExit, ssExit64, L, s_bl64p, s_pr, bt, b64);
        if (c + 8 < 40) load8s(R3, Barr, 319 - (c + 8) * 8, -1, lane);
        beta_chunk<N64>(R4, 319 - (c + 4) * 8, lane, ssExit, ssExit64, L, s_bl64p, s_pr, bt, b64);
        if (c + 9 < 40) load8s(R4, Barr, 319 - (c + 9) * 8, -1, lane);
    }
}

// ---------------- Kernel 2: concurrent fwd/bwd DP + fused delay ------------
// One block = 2 waves per example. Wave 0: alpha sweep; wave 1: beta sweep
// (stores s_pr[t][u] = label+beta[t,u+1]); then a joint gamma pass over LDS.
// s_alpha/s_pr have trash rows (clamped stores) -> no exec masks in the loop.
__global__ __launch_bounds__(128, 1) void k_dp(const float* __restrict__ Aarr_,
                                               const float* __restrict__ Barr_,
                                               const float* __restrict__ p6arr_,
                                               const float* __restrict__ bl64_,
                                               const int* __restrict__ act_lens,
                                               const int* __restrict__ label_lens,
                                               float* __restrict__ partials) {
    __shared__ float s_alpha[258 * UU];           // rows: trash,0..255,trash
    __shared__ float s_pr[258 * UU];
    __shared__ float s_bl64p[TM + 2];             // [0]=pad, [1+t]=bl64[t]
    __shared__ float s_p6[ND];
    __shared__ float s_logZ;
    __shared__ float s_red[2];
    const int b    = blockIdx.x;
    const int tid  = threadIdx.x;
    const int lane = tid & 63;
    const int wv   = tid >> 6;
    const float* Aarr = Aarr_ + (size_t)b * ND * WROW;
    const float* Barr = Barr_ + (size_t)b * ND * WROW;

    if (tid == 0) { s_bl64p[0] = NEGF; s_bl64p[TM + 1] = NEGF; }
    for (int i = tid; i < TM; i += 128) s_bl64p[i + 1] = bl64_[b * TM + i];
    for (int i = tid; i < ND; i += 128) s_p6[i] = p6arr_[b * ND + i];
    __syncthreads();

    const int T = act_lens[b];
    const int L = label_lens[b];
    const int t_last = T - 1;

    if (wv == 0) {
        if (lane == 0) s_alpha[1 * UU + 0] = 0.0f;     // alpha[0,0] = 0
        float aE;
        if (L == UU) {
            aE = alpha_sweep<true >(Aarr, lane, t_last, L, s_bl64p, s_p6, s_alpha);
        } else {
            alpha_sweep<false>(Aarr, lane, t_last, L, s_bl64p, s_p6, s_alpha);
            aE = s_alpha[(t_last + 1) * UU + L];       // hoisted capture
        }
        const float blankLast = (L < UU) ? Aarr[(size_t)(t_last + L) * WROW + 2 * L]
                                         : s_bl64p[t_last + 1];
        if (lane == 0) s_logZ = aE + blankLast;        // base-2 units
    } else {
        const int ssExit   = t_last + L;               // lane==L only if L<64
        const int ssExit64 = (L == UU) ? (t_last + 64) : -1;
        if (L == UU) beta_sweep<true >(Barr, lane, ssExit, ssExit64, L, s_bl64p, s_pr);
        else         beta_sweep<false>(Barr, lane, ssExit, ssExit64, L, s_bl64p, s_pr);
    }
    __syncthreads();

    // ---- gamma pass: dsum = sum exp2(alpha + pr - logZ) * t/T ----
    const float logZ = s_logZ;
    const float invT = 1.0f / (float)T;
    float dsum = 0.0f;
#pragma unroll 8
    for (int idx = tid; idx < TM * UU; idx += 128) {
        const int t = idx >> 6;
        dsum = __fmaf_rn(aexp2(s_alpha[idx + UU] + s_pr[idx + UU] - logZ),
                         (float)t * invT, dsum);
    }
#pragma unroll
    for (int o = 32; o; o >>= 1) dsum += __shfl_xor(dsum, o);
    if (lane == 0) s_red[wv] = dsum;
    __syncthreads();
    if (tid == 0) {
        partials[2 * b + 0] = -logZ * LN2;        // loss_rnnt_b (nat units)
        partials[2 * b + 1] = s_red[0] + s_red[1];
    }
}

// ---------------- Kernel 3: final reduction ----------------
__global__ void k_reduce(const float* __restrict__ partials, float* __restrict__ out) {
    if (threadIdx.x == 0 && blockIdx.x == 0) {
        float rn = 0.0f, dl = 0.0f;
        for (int b = 0; b < BB; ++b) {
            rn += partials[2 * b + 0];
            dl += partials[2 * b + 1];
        }
        out[0] = rn + dl;   // loss_total  (DELAY_SCALE = 1)
        out[1] = rn;        // loss_rnnt
        out[2] = dl;        // loss_delay
    }
}

extern "C" void kernel_launch(void* const* d_in, const int* in_sizes, int n_in,
                              void* d_out, int out_size, void* d_ws, size_t ws_size,
                              hipStream_t stream) {
    const float* acts       = (const float*)d_in[0];
    const int*   labels     = (const int*)d_in[1];
    const int*   act_lens   = (const int*)d_in[2];
    const int*   label_lens = (const int*)d_in[3];

    float* ws       = (float*)d_ws;
    float* Aarr     = ws;                               // B*ND*WROW = 655360 f
    float* Barr     = Aarr + (size_t)BB * ND * WROW;    // B*ND*WROW = 655360 f
    float* p6arr    = Barr + (size_t)BB * ND * WROW;    // B*ND      =   5120 f
    float* bl64     = p6arr + BB * ND;                  // B*TM      =   4096 f
    float* partials = bl64 + BB * TM;                   // 32 f
    // total ~5.3 MB of ws

    const int nfill4 = (2 * BB * ND * WROW + BB * ND) / 4;  // Aarr+Barr+p6arr
    k_fill<<<(nfill4 + 255) / 256, 256, 0, stream>>>(ws, nfill4);

    const int rows = BB * TM * U1;
    k_lse<<<(rows + 3) / 4, 256, 0, stream>>>(acts, labels, Aarr, Barr, p6arr, bl64);
    k_dp<<<BB, 128, 0, stream>>>(Aarr, Barr, p6arr, bl64, act_lens, label_lens, partials);
    k_reduce<<<1, 64, 0, stream>>>(partials, (float*)d_out);
}